// Round 4
// baseline (5698.542 us; speedup 1.0000x reference)
//
#include <hip/hip_runtime.h>

// MomentumDelta: B=64, L=2048, H=256, V=32000, beta=0.9
// Reference is float32; harness may deliver float inputs as fp32 OR bf16.
// This round: on-device dtype detection (sample even u16s of embed — fp32
// low-mantissa halves look like garbage bf16, real bf16 doesn't), templated
// dual load paths, output dtype follows the detected input dtype.
//
// Pipeline:
//   enc:  h[tok] = LN(e + FFN(e)), e = embed[seq]   -> ws (bf16, 64 MiB)
//   scan: per (b, i-block): M in regs; per 32-chunk: G=KK^T in LDS,
//         U=K M0^T, RHS, fwd-substitute (I+B)D=RHS, rank-32 M update; y=Mq.
//   r1:   zT = (y @ rp_W + rp_b)^T -> ws start (h dead after scan)
//   r2:   out = z @ out_W + out_b  -> d_out

#define B_ 64
#define L_ 2048
#define H_ 256
#define V_ 32000

typedef unsigned short u16;

__device__ __forceinline__ float b2f(u16 u){ union{unsigned x; float f;} z; z.x = ((unsigned)u)<<16; return z.f; }
__device__ __forceinline__ u16 f2b(float f){ union{float f; unsigned x;} z; z.f = f; unsigned r = z.x + 0x7FFFu + ((z.x>>16)&1u); return (u16)(r>>16); }
__device__ __forceinline__ float san(float v){ return (v == v && v > -1e30f && v < 1e30f) ? v : 0.f; }

template<bool F32> __device__ __forceinline__ float ldw(const void* p, long i){
  if (F32) return ((const float*)p)[i];
  return b2f(((const u16*)p)[i]);
}
template<bool F32> __device__ __forceinline__ float4 ld4(const void* p, long i){ // i % 4 == 0
  if (F32) return *(const float4*)((const float*)p + i);
  ushort4 u = *(const ushort4*)((const u16*)p + i);
  return make_float4(b2f(u.x), b2f(u.y), b2f(u.z), b2f(u.w));
}

// All 256 threads of a block must call this (uses __syncthreads_count).
// Returns 1 if `embed` holds fp32 data, 0 if bf16.
__device__ __forceinline__ int detect_f32(const void* embed){
  const u16* e = (const u16*)embed;
  unsigned v = e[2 * (threadIdx.x & 255)];
  int ex = (v >> 7) & 0xFF;
  int pl = (ex >= 0x66 && ex <= 0x7D) || ((v & 0x7FFFu) == 0u);
  int cnt = __syncthreads_count(pl);
  return cnt < 128;
}

// ---------------------------------------------------------------- sentinel --
__global__ __launch_bounds__(256) void sentinel_kernel(const void* embed, void* out, float val)
{
  int f32 = detect_f32(embed);
  long idx = (long)blockIdx.x * 256 + threadIdx.x;
  if (idx < (long)B_ * V_){
    if (f32) ((float*)out)[idx] = val;
    else     ((u16*)out)[idx]   = f2b(val);
  }
}

// ---------------------------------------------------------------- encoder ---
template<bool F32>
__device__ __forceinline__ void enc_body(
    u16* sm,
    const int* __restrict__ seq, const void* __restrict__ embed,
    const void* __restrict__ W1, const void* __restrict__ b1,
    const void* __restrict__ W2, const void* __restrict__ b2,
    const void* __restrict__ gamma, const void* __restrict__ beta,
    u16* __restrict__ h)
{
  // 64KB: eT [256][32] (16KB) | t1T [512][32] (32KB) | xb [32][256] (16KB)
  u16* eT  = sm;
  u16* t1T = sm + 8192;
  u16* xb  = sm + 24576;
  float* stats = (float*)sm;  // aliases eT after its last use (mu[32], rstd[32])

  const int tid = threadIdx.x;
  const long tok0 = (long)blockIdx.x * 32;

  // gather 32 token embeddings, transposed eT[c][r]
  for (int idx = tid; idx < 8192; idx += 256){
    int r = idx >> 8, c = idx & 255;
    int tk = seq[tok0 + r];
    tk = (tk >= 0 && tk < V_) ? tk : 0;
    eT[c*32 + r] = f2b(ldw<F32>(embed, (long)tk*H_ + c));
  }
  __syncthreads();

  const int jg = tid & 31, rg = tid >> 5;
  const int r0 = rg * 4;

  // GEMM1: T1 = relu(E @ W1 + b1)   E:[32,256] W1:[256,512]
  for (int sl = 0; sl < 4; ++sl){
    const int j0 = sl*128 + jg*4;
    float acc[4][4] = {{0.f}};
    for (int c = 0; c < 256; ++c){
      ushort4 a4 = *(const ushort4*)&eT[c*32 + r0];
      float4 w = ld4<F32>(W1, (long)c*512 + j0);
      float a0=b2f(a4.x), a1=b2f(a4.y), a2=b2f(a4.z), a3=b2f(a4.w);
      acc[0][0]+=a0*w.x; acc[0][1]+=a0*w.y; acc[0][2]+=a0*w.z; acc[0][3]+=a0*w.w;
      acc[1][0]+=a1*w.x; acc[1][1]+=a1*w.y; acc[1][2]+=a1*w.z; acc[1][3]+=a1*w.w;
      acc[2][0]+=a2*w.x; acc[2][1]+=a2*w.y; acc[2][2]+=a2*w.z; acc[2][3]+=a2*w.w;
      acc[3][0]+=a3*w.x; acc[3][1]+=a3*w.y; acc[3][2]+=a3*w.z; acc[3][3]+=a3*w.w;
    }
    for (int jj = 0; jj < 4; ++jj){
      float bb = ldw<F32>(b1, j0+jj);
      ushort4 o;
      o.x = f2b(fmaxf(acc[0][jj]+bb, 0.f));
      o.y = f2b(fmaxf(acc[1][jj]+bb, 0.f));
      o.z = f2b(fmaxf(acc[2][jj]+bb, 0.f));
      o.w = f2b(fmaxf(acc[3][jj]+bb, 0.f));
      *(ushort4*)&t1T[(j0+jj)*32 + r0] = o;
    }
  }
  __syncthreads();

  // GEMM2 + bias + residual: X = T1 @ W2 + b2 + E
  for (int sl = 0; sl < 2; ++sl){
    const int co0 = sl*128 + jg*4;
    float acc[4][4] = {{0.f}};
    for (int c = 0; c < 512; ++c){
      ushort4 a4 = *(const ushort4*)&t1T[c*32 + r0];
      float4 w = ld4<F32>(W2, (long)c*256 + co0);
      float a0=b2f(a4.x), a1=b2f(a4.y), a2=b2f(a4.z), a3=b2f(a4.w);
      acc[0][0]+=a0*w.x; acc[0][1]+=a0*w.y; acc[0][2]+=a0*w.z; acc[0][3]+=a0*w.w;
      acc[1][0]+=a1*w.x; acc[1][1]+=a1*w.y; acc[1][2]+=a1*w.z; acc[1][3]+=a1*w.w;
      acc[2][0]+=a2*w.x; acc[2][1]+=a2*w.y; acc[2][2]+=a2*w.z; acc[2][3]+=a2*w.w;
      acc[3][0]+=a3*w.x; acc[3][1]+=a3*w.y; acc[3][2]+=a3*w.z; acc[3][3]+=a3*w.w;
    }
    float bb0 = ldw<F32>(b2, co0+0), bb1 = ldw<F32>(b2, co0+1);
    float bb2 = ldw<F32>(b2, co0+2), bb3 = ldw<F32>(b2, co0+3);
    for (int rr = 0; rr < 4; ++rr){
      float x0 = acc[rr][0] + bb0 + b2f(eT[(co0+0)*32 + r0+rr]);
      float x1 = acc[rr][1] + bb1 + b2f(eT[(co0+1)*32 + r0+rr]);
      float x2 = acc[rr][2] + bb2 + b2f(eT[(co0+2)*32 + r0+rr]);
      float x3 = acc[rr][3] + bb3 + b2f(eT[(co0+3)*32 + r0+rr]);
      ushort4 o; o.x=f2b(x0); o.y=f2b(x1); o.z=f2b(x2); o.w=f2b(x3);
      *(ushort4*)&xb[(r0+rr)*256 + co0] = o;
    }
  }
  __syncthreads();

  // LayerNorm over H
  if (tid < 32){
    float s = 0.f, q = 0.f;
    for (int c = 0; c < 256; ++c){ float v = b2f(xb[tid*256 + c]); s += v; q += v*v; }
    float mu = s * (1.f/256.f);
    float var = q * (1.f/256.f) - mu*mu;
    stats[tid] = mu;
    stats[32 + tid] = 1.f / sqrtf(fmaxf(var, 0.f) + 1e-5f);
  }
  __syncthreads();
  for (int idx = tid; idx < 8192; idx += 256){
    int r = idx >> 8, c = idx & 255;
    float hv = (b2f(xb[idx]) - stats[r]) * stats[32+r] * ldw<F32>(gamma, c) + ldw<F32>(beta, c);
    h[(tok0 + r)*H_ + c] = f2b(san(hv));
  }
}

__global__ __launch_bounds__(256) void enc_kernel(
    const int* __restrict__ seq, const void* __restrict__ embed,
    const void* __restrict__ W1, const void* __restrict__ b1,
    const void* __restrict__ W2, const void* __restrict__ b2,
    const void* __restrict__ gamma, const void* __restrict__ beta,
    u16* __restrict__ h)
{
  __shared__ __align__(16) u16 sm[32768];
  if (detect_f32(embed)) enc_body<true >(sm, seq, embed, W1, b1, W2, b2, gamma, beta, h);
  else                   enc_body<false>(sm, seq, embed, W1, b1, W2, b2, gamma, beta, h);
}

// ----------------------------------------------------------------- scan ------
// grid 256 = (b:64) x (ib:4).  Thread (il = tid>>2, jb = tid&3) owns
// M[ib*64+il][jb*64 .. jb*64+63] in 64 VGPRs.  Reads internal bf16 h only.
__global__ __launch_bounds__(256) void scan_kernel(
    const u16* __restrict__ h, float* __restrict__ y)
{
  __shared__ float k_l[8192];     // chunk K, interleaved [t][jj][jb][e] (32KB)
  __shared__ float u_l[2048];     // U = K M0^T  [t][il]
  __shared__ float rhs_l[2048];
  __shared__ float d_l[2048];
  __shared__ float g_l[32*33];    // Gram, lower triangle + diag
  __shared__ float inv_l[32];
  __shared__ float bp[33];
  __shared__ float q_l[256];

  const int tid = threadIdx.x;
  const int b = blockIdx.x >> 2, ib = blockIdx.x & 3;
  const int jb = tid & 3, il = tid >> 2;
  const int q4 = tid >> 2;

  float M[64];
  #pragma unroll
  for (int m = 0; m < 64; ++m) M[m] = 0.f;
  if (tid < 33) bp[tid] = powf(0.9f, (float)tid);

  const u16* hb = h + (long)b * L_ * H_;

  for (int ch = 0; ch < 64; ++ch){
    const int t0 = ch*32;
    const int C = (2047 - t0 < 32) ? (2047 - t0) : 32;

    for (int idx = tid; idx < 8192; idx += 256){
      int t = idx >> 8, j = idx & 255;
      float v = (t < C) ? san(b2f(hb[(t0 + t)*H_ + j])) : 0.f;
      k_l[t*256 + ((j & 63) >> 2)*16 + (j >> 6)*4 + (j & 3)] = v;
    }
    __syncthreads();

    // G[t][s] for s<=t
    for (int it = 0; it < 16; ++it){
      int p = it*64 + q4;
      int t = p >> 5, s = p & 31;
      if (s <= t){
        const float4* kt = (const float4*)&k_l[t*256];
        const float4* ks = (const float4*)&k_l[s*256];
        float acc = 0.f;
        #pragma unroll
        for (int jj = 0; jj < 16; ++jj){
          float4 a = kt[jj*4 + jb];
          float4 c = ks[jj*4 + jb];
          acc += a.x*c.x + a.y*c.y + a.z*c.z + a.w*c.w;
        }
        acc += __shfl_xor(acc, 1);
        acc += __shfl_xor(acc, 2);
        if (jb == 0) g_l[t*33 + s] = acc;
      }
    }
    __syncthreads();
    if (tid < 32) inv_l[tid] = 1.f / (g_l[tid*33 + tid] + 1e-6f);
    __syncthreads();

    // U[t][il] = sum_j M[il][j] k[t][j]
    for (int t = 0; t < C; ++t){
      const float4* kp = (const float4*)&k_l[t*256];
      float p = 0.f;
      #pragma unroll
      for (int jj = 0; jj < 16; ++jj){
        float4 kv = kp[jj*4 + jb];
        p += M[jj*4+0]*kv.x + M[jj*4+1]*kv.y + M[jj*4+2]*kv.z + M[jj*4+3]*kv.w;
      }
      p += __shfl_xor(p, 1);
      p += __shfl_xor(p, 2);
      if (jb == 0) u_l[t*64 + il] = p;
    }
    __syncthreads();

    // RHS[t][i] = k_t[i] - beta^t * U[t][i] / nk_t
    for (int idx = tid; idx < (C << 6); idx += 256){
      int t = idx >> 6, ii = idx & 63;
      int j = ib*64 + ii;
      float kv = k_l[t*256 + ((j & 63) >> 2)*16 + (j >> 6)*4 + (j & 3)];
      rhs_l[idx] = kv - bp[t] * u_l[idx] * inv_l[t];
    }
    __syncthreads();

    // forward substitution (I+B) D = RHS, one wave, lane = column ii
    if (tid < 64){
      for (int t = 0; t < C; ++t){
        float f = 0.1f * inv_l[t];
        float acc = rhs_l[(t << 6) + tid];
        for (int s = 0; s < t; ++s)
          acc -= f * bp[t-1-s] * g_l[t*33 + s] * d_l[(s << 6) + tid];
        d_l[(t << 6) + tid] = san(acc);
      }
    }
    __syncthreads();

    // M = beta^C * M + sum_t (1-beta) beta^{C-1-t} d_t[i] k_t[j]
    const float bC = bp[C];
    #pragma unroll
    for (int m = 0; m < 64; ++m) M[m] *= bC;
    for (int t = 0; t < C; ++t){
      float dw = d_l[t*64 + il] * (0.1f * bp[C-1-t]);
      const float4* kp = (const float4*)&k_l[t*256];
      #pragma unroll
      for (int jj = 0; jj < 16; ++jj){
        float4 kv = kp[jj*4 + jb];
        M[jj*4+0] += dw*kv.x; M[jj*4+1] += dw*kv.y;
        M[jj*4+2] += dw*kv.z; M[jj*4+3] += dw*kv.w;
      }
    }
    __syncthreads();
  }

  // y[b][i] = sum_j M[i][j] q[j],  q = h[b, L-1]
  q_l[tid] = san(b2f(hb[(L_-1)*H_ + tid]));
  __syncthreads();
  float p = 0.f;
  #pragma unroll
  for (int jj = 0; jj < 16; ++jj){
    float4 qv = ((const float4*)q_l)[jb*16 + jj];
    p += M[jj*4+0]*qv.x + M[jj*4+1]*qv.y + M[jj*4+2]*qv.z + M[jj*4+3]*qv.w;
  }
  p += __shfl_xor(p, 1);
  p += __shfl_xor(p, 2);
  if (jb == 0) y[b*H_ + ib*64 + il] = san(p);
}

// -------------------------------------------------- z = y @ rp_W + rp_b ------
template<bool F32>
__device__ __forceinline__ void r1_body(
    float* yl, const float* __restrict__ y, const void* __restrict__ rpW,
    const void* __restrict__ rpb, float* __restrict__ zT)
{
  const int b = blockIdx.x, tid = threadIdx.x;
  yl[tid] = san(y[b*H_ + tid]);
  __syncthreads();
  float acc = ldw<F32>(rpb, tid);
  for (int j = 0; j < 256; ++j) acc += yl[j] * ldw<F32>(rpW, (long)j*H_ + tid);
  zT[tid*B_ + b] = san(acc);  // transposed [i][b] for r2
}

__global__ __launch_bounds__(256) void r1_kernel(
    const void* __restrict__ embed, const float* __restrict__ y,
    const void* __restrict__ rpW, const void* __restrict__ rpb,
    float* __restrict__ zT)
{
  __shared__ float yl[256];
  if (detect_f32(embed)) r1_body<true >(yl, y, rpW, rpb, zT);
  else                   r1_body<false>(yl, y, rpW, rpb, zT);
}

// ------------------------------------------------ out = z @ out_W + out_b ----
template<bool F32>
__device__ __forceinline__ void r2_body(
    float* zl, const float* __restrict__ zT, const void* __restrict__ outW,
    const void* __restrict__ outb, void* __restrict__ out)
{
  const int tid = threadIdx.x;
  const int v = blockIdx.x*256 + tid;
  for (int idx = tid; idx < 16384; idx += 256) zl[idx] = zT[idx];
  __syncthreads();

  float ob = ldw<F32>(outb, v);
  float acc[64];
  #pragma unroll
  for (int bb = 0; bb < 64; ++bb) acc[bb] = ob;

  for (int i = 0; i < 256; ++i){
    float w = ldw<F32>(outW, (long)i*V_ + v);
    const float4* zp = (const float4*)&zl[i*64];
    #pragma unroll
    for (int q = 0; q < 16; ++q){
      float4 z4 = zp[q];
      acc[q*4+0] += w*z4.x; acc[q*4+1] += w*z4.y;
      acc[q*4+2] += w*z4.z; acc[q*4+3] += w*z4.w;
    }
  }
  if (F32){
    for (int bb = 0; bb < 64; ++bb) ((float*)out)[(long)bb*V_ + v] = san(acc[bb]);
  } else {
    for (int bb = 0; bb < 64; ++bb) ((u16*)out)[(long)bb*V_ + v] = f2b(san(acc[bb]));
  }
}

__global__ __launch_bounds__(256) void r2_kernel(
    const void* __restrict__ embed, const float* __restrict__ zT,
    const void* __restrict__ outW, const void* __restrict__ outb,
    void* __restrict__ out)
{
  __shared__ float zl[16384];  // [i][b] 64KB
  if (detect_f32(embed)) r2_body<true >(zl, zT, outW, outb, out);
  else                   r2_body<false>(zl, zT, outW, outb, out);
}

// ---------------------------------------------------------------- launch -----
extern "C" void kernel_launch(void* const* d_in, const int* in_sizes, int n_in,
                              void* d_out, int out_size, void* d_ws, size_t ws_size,
                              hipStream_t stream) {
  // --- guards (host-side, deterministic, graph-safe) ---
  bool sizes_ok = (n_in == 12) && in_sizes
      && in_sizes[0] == B_*L_ && in_sizes[1] == V_*H_ && in_sizes[2] == H_*2*H_
      && in_sizes[3] == 2*H_  && in_sizes[4] == 2*H_*H_ && in_sizes[5] == H_
      && in_sizes[6] == H_    && in_sizes[7] == H_    && in_sizes[8] == H_*H_
      && in_sizes[9] == H_    && in_sizes[10] == H_*V_ && in_sizes[11] == V_;
  if (!sizes_ok){
    sentinel_kernel<<<(B_*V_ + 255)/256, 256, 0, stream>>>(d_in ? d_in[1] : d_out, d_out, 2000.0f);
    return;
  }
  if (ws_size < 67108864ull){
    sentinel_kernel<<<(B_*V_ + 255)/256, 256, 0, stream>>>(d_in[1], d_out, 1000.0f);
    return;
  }

  const int* seq   = (const int*)d_in[0];
  const void* embed= d_in[1];
  const void* W1   = d_in[2];
  const void* b1   = d_in[3];
  const void* W2   = d_in[4];
  const void* b2   = d_in[5];
  const void* gamma= d_in[6];
  const void* beta = d_in[7];
  const void* rpW  = d_in[8];
  const void* rpb  = d_in[9];
  const void* outW = d_in[10];
  const void* outb = d_in[11];

  // ws: h = 64*2048*256 bf16 = 67,108,864 B.  zT reuses ws start AFTER scan
  // consumed h (stream-ordered).  y (fp32, 64KB) lives in d_out's first 64KB,
  // consumed by r1, then fully overwritten by r2.
  u16*   h  = (u16*)d_ws;
  float* zT = (float*)d_ws;
  float* y  = (float*)d_out;

  enc_kernel <<<4096, 256, 0, stream>>>(seq, embed, W1, b1, W2, b2, gamma, beta, h);
  scan_kernel<<< 256, 256, 0, stream>>>(h, y);
  r1_kernel  <<<  64, 256, 0, stream>>>(embed, y, rpW, rpb, zT);
  r2_kernel  <<< 125, 256, 0, stream>>>(embed, zT, outW, outb, d_out);
}

// Round 5
// 3725.587 us; speedup vs baseline: 1.5296x; 1.5296x over previous
//
#include <hip/hip_runtime.h>

// MomentumDelta: B=64, L=2048, H=256, V=32000, beta=0.9
// Inputs are fp32 (confirmed R4 via on-device detection); detection retained.
// R5: scan rewritten around v_mfma_f32_32x32x16_bf16:
//   G = K K^T          (wave1, 16 MFMAs)
//   U = K M^T          (wave0, 32 MFMAs, M split hi/lo double-bf16)
//   dM^T = K^T (w.D)   (both waves, 16 MFMAs, merged into fp32 M in LDS)
// M state: LDS fp32 [32][257]; K staged once/chunk, XOR-swizzled 16B units.
// Grid 512 = 64 b x 8 row-blocks(32 rows), 128 thr, 57.9KB LDS -> 2 blk/CU.

#define B_ 64
#define L_ 2048
#define H_ 256
#define V_ 32000

typedef unsigned short u16;
typedef __attribute__((ext_vector_type(8))) short bf16x8;
typedef __attribute__((ext_vector_type(16))) float f32x16;

__device__ __forceinline__ float b2f(u16 u){ union{unsigned x; float f;} z; z.x = ((unsigned)u)<<16; return z.f; }
__device__ __forceinline__ u16 f2b(float f){ union{float f; unsigned x;} z; z.f = f; unsigned r = z.x + 0x7FFFu + ((z.x>>16)&1u); return (u16)(r>>16); }
__device__ __forceinline__ float san(float v){ return (v == v && v > -1e30f && v < 1e30f) ? v : 0.f; }

template<bool F32> __device__ __forceinline__ float ldw(const void* p, long i){
  if (F32) return ((const float*)p)[i];
  return b2f(((const u16*)p)[i]);
}
template<bool F32> __device__ __forceinline__ float4 ld4(const void* p, long i){ // i % 4 == 0
  if (F32) return *(const float4*)((const float*)p + i);
  ushort4 u = *(const ushort4*)((const u16*)p + i);
  return make_float4(b2f(u.x), b2f(u.y), b2f(u.z), b2f(u.w));
}

// All threads of the block must call (uses __syncthreads_count).
__device__ __forceinline__ int detect_f32(const void* embed){
  const u16* e = (const u16*)embed;
  unsigned v = e[2 * (threadIdx.x & 255)];
  int ex = (v >> 7) & 0xFF;
  int pl = (ex >= 0x66 && ex <= 0x7D) || ((v & 0x7FFFu) == 0u);
  int cnt = __syncthreads_count(pl);
  return cnt < 128;
}

// ---------------------------------------------------------------- sentinel --
__global__ __launch_bounds__(256) void sentinel_kernel(const void* embed, void* out, float val)
{
  int f32 = detect_f32(embed);
  long idx = (long)blockIdx.x * 256 + threadIdx.x;
  if (idx < (long)B_ * V_){
    if (f32) ((float*)out)[idx] = val;
    else     ((u16*)out)[idx]   = f2b(val);
  }
}

// ---------------------------------------------------------------- encoder ---
template<bool F32>
__device__ __forceinline__ void enc_body(
    u16* sm,
    const int* __restrict__ seq, const void* __restrict__ embed,
    const void* __restrict__ W1, const void* __restrict__ b1,
    const void* __restrict__ W2, const void* __restrict__ b2,
    const void* __restrict__ gamma, const void* __restrict__ beta,
    u16* __restrict__ h)
{
  u16* eT  = sm;           // [256][32]
  u16* t1T = sm + 8192;    // [512][32]
  u16* xb  = sm + 24576;   // [32][256]
  float* stats = (float*)sm;

  const int tid = threadIdx.x;
  const long tok0 = (long)blockIdx.x * 32;

  for (int idx = tid; idx < 8192; idx += 256){
    int r = idx >> 8, c = idx & 255;
    int tk = seq[tok0 + r];
    tk = (tk >= 0 && tk < V_) ? tk : 0;
    eT[c*32 + r] = f2b(ldw<F32>(embed, (long)tk*H_ + c));
  }
  __syncthreads();

  const int jg = tid & 31, rg = tid >> 5;
  const int r0 = rg * 4;

  for (int sl = 0; sl < 4; ++sl){
    const int j0 = sl*128 + jg*4;
    float acc[4][4] = {{0.f}};
    for (int c = 0; c < 256; ++c){
      ushort4 a4 = *(const ushort4*)&eT[c*32 + r0];
      float4 w = ld4<F32>(W1, (long)c*512 + j0);
      float a0=b2f(a4.x), a1=b2f(a4.y), a2=b2f(a4.z), a3=b2f(a4.w);
      acc[0][0]+=a0*w.x; acc[0][1]+=a0*w.y; acc[0][2]+=a0*w.z; acc[0][3]+=a0*w.w;
      acc[1][0]+=a1*w.x; acc[1][1]+=a1*w.y; acc[1][2]+=a1*w.z; acc[1][3]+=a1*w.w;
      acc[2][0]+=a2*w.x; acc[2][1]+=a2*w.y; acc[2][2]+=a2*w.z; acc[2][3]+=a2*w.w;
      acc[3][0]+=a3*w.x; acc[3][1]+=a3*w.y; acc[3][2]+=a3*w.z; acc[3][3]+=a3*w.w;
    }
    for (int jj = 0; jj < 4; ++jj){
      float bb = ldw<F32>(b1, j0+jj);
      ushort4 o;
      o.x = f2b(fmaxf(acc[0][jj]+bb, 0.f));
      o.y = f2b(fmaxf(acc[1][jj]+bb, 0.f));
      o.z = f2b(fmaxf(acc[2][jj]+bb, 0.f));
      o.w = f2b(fmaxf(acc[3][jj]+bb, 0.f));
      *(ushort4*)&t1T[(j0+jj)*32 + r0] = o;
    }
  }
  __syncthreads();

  for (int sl = 0; sl < 2; ++sl){
    const int co0 = sl*128 + jg*4;
    float acc[4][4] = {{0.f}};
    for (int c = 0; c < 512; ++c){
      ushort4 a4 = *(const ushort4*)&t1T[c*32 + r0];
      float4 w = ld4<F32>(W2, (long)c*256 + co0);
      float a0=b2f(a4.x), a1=b2f(a4.y), a2=b2f(a4.z), a3=b2f(a4.w);
      acc[0][0]+=a0*w.x; acc[0][1]+=a0*w.y; acc[0][2]+=a0*w.z; acc[0][3]+=a0*w.w;
      acc[1][0]+=a1*w.x; acc[1][1]+=a1*w.y; acc[1][2]+=a1*w.z; acc[1][3]+=a1*w.w;
      acc[2][0]+=a2*w.x; acc[2][1]+=a2*w.y; acc[2][2]+=a2*w.z; acc[2][3]+=a2*w.w;
      acc[3][0]+=a3*w.x; acc[3][1]+=a3*w.y; acc[3][2]+=a3*w.z; acc[3][3]+=a3*w.w;
    }
    float bb0 = ldw<F32>(b2, co0+0), bb1 = ldw<F32>(b2, co0+1);
    float bb2 = ldw<F32>(b2, co0+2), bb3 = ldw<F32>(b2, co0+3);
    for (int rr = 0; rr < 4; ++rr){
      float x0 = acc[rr][0] + bb0 + b2f(eT[(co0+0)*32 + r0+rr]);
      float x1 = acc[rr][1] + bb1 + b2f(eT[(co0+1)*32 + r0+rr]);
      float x2 = acc[rr][2] + bb2 + b2f(eT[(co0+2)*32 + r0+rr]);
      float x3 = acc[rr][3] + bb3 + b2f(eT[(co0+3)*32 + r0+rr]);
      ushort4 o; o.x=f2b(x0); o.y=f2b(x1); o.z=f2b(x2); o.w=f2b(x3);
      *(ushort4*)&xb[(r0+rr)*256 + co0] = o;
    }
  }
  __syncthreads();

  if (tid < 32){
    float s = 0.f, q = 0.f;
    for (int c = 0; c < 256; ++c){ float v = b2f(xb[tid*256 + c]); s += v; q += v*v; }
    float mu = s * (1.f/256.f);
    float var = q * (1.f/256.f) - mu*mu;
    stats[tid] = mu;
    stats[32 + tid] = 1.f / sqrtf(fmaxf(var, 0.f) + 1e-5f);
  }
  __syncthreads();
  for (int idx = tid; idx < 8192; idx += 256){
    int r = idx >> 8, c = idx & 255;
    float hv = (b2f(xb[idx]) - stats[r]) * stats[32+r] * ldw<F32>(gamma, c) + ldw<F32>(beta, c);
    h[(tok0 + r)*H_ + c] = f2b(san(hv));
  }
}

__global__ __launch_bounds__(256) void enc_kernel(
    const int* __restrict__ seq, const void* __restrict__ embed,
    const void* __restrict__ W1, const void* __restrict__ b1,
    const void* __restrict__ W2, const void* __restrict__ b2,
    const void* __restrict__ gamma, const void* __restrict__ beta,
    u16* __restrict__ h)
{
  __shared__ __align__(16) u16 sm[32768];
  if (detect_f32(embed)) enc_body<true >(sm, seq, embed, W1, b1, W2, b2, gamma, beta, h);
  else                   enc_body<false>(sm, seq, embed, W1, b1, W2, b2, gamma, beta, h);
}

// ------------------------------------------------------------- scan (MFMA) --
// grid 512 = b(64) x ib(8); block owns M rows [ib*32, ib*32+32), 128 threads.
// wave0: U = K M^T (hi/lo).  wave1: G = K K^T.  both: update via dM^T = K^T(wD).
__global__ __launch_bounds__(128) void scan_kernel(
    const u16* __restrict__ h, float* __restrict__ y)
{
  __shared__ __align__(16) float M_l[32*257];  // state fp32 [i][j], stride 257
  __shared__ __align__(16) u16  k_l[32*256];   // [t][j] bf16, XOR-swizzled 16B units
  __shared__ float d_l[32*33];                 // U -> RHS -> D   [t][i]
  __shared__ float g_l[32*33];                 // Gram [t][s] (q reuse at end)
  __shared__ float bp[33];

  const int tid = threadIdx.x;
  const int b = blockIdx.x >> 3, ib = blockIdx.x & 7;
  const int lane = tid & 63, wv = tid >> 6;
  const int col = lane & 31, hw = lane >> 5;

  for (int idx = tid; idx < 32*257; idx += 128) M_l[idx] = 0.f;
  if (tid < 33) bp[tid] = powf(0.9f, (float)tid);
  const u16* hb = h + (long)b * L_ * H_;
  __syncthreads();

  for (int ch = 0; ch < 64; ++ch){
    const int t0 = ch*32;
    const int C = (2047 - t0 < 32) ? (2047 - t0) : 32;

    { // stage chunk K: thread -> row t = tid>>2, 64 bf16 at j0
      const int t = tid >> 2, j0 = (tid & 3) * 64;
      const uint4* gp = (const uint4*)(hb + (long)(t0 + t)*H_ + j0);
      #pragma unroll
      for (int c = 0; c < 8; ++c){
        uint4 v = (t < C) ? gp[c] : make_uint4(0u,0u,0u,0u);
        int unit = (j0 >> 3) + c;
        int phys = unit ^ (t & 7);
        *(uint4*)&k_l[t*256 + phys*8] = v;
      }
    }
    __syncthreads();

    if (wv == 1){
      // G = K K^T (A-pattern == B-pattern: row = lane&31, 8 contiguous k)
      f32x16 acc; for (int r=0;r<16;++r) acc[r]=0.f;
      #pragma unroll
      for (int s = 0; s < 16; ++s){
        int phys = (s*2 + hw) ^ (col & 7);
        bf16x8 a = *(const bf16x8*)&k_l[col*256 + phys*8];
        acc = __builtin_amdgcn_mfma_f32_32x32x16_bf16(a, a, acc, 0, 0, 0);
      }
      #pragma unroll
      for (int r = 0; r < 16; ++r){
        int row = (r&3) + 8*(r>>2) + 4*hw;     // t
        g_l[row*33 + col] = acc[r];            // col = s
      }
    } else {
      // U[t][i] = sum_j K[t][j] M[i][j], M = hi + lo (double-bf16)
      f32x16 acc; for (int r=0;r<16;++r) acc[r]=0.f;
      for (int s = 0; s < 16; ++s){
        int phys = (s*2 + hw) ^ (col & 7);
        bf16x8 a = *(const bf16x8*)&k_l[col*256 + phys*8];   // col = t here
        bf16x8 bh, bl;
        const float* mp = &M_l[col*257 + s*16 + hw*8];       // col = i here
        #pragma unroll
        for (int c = 0; c < 8; ++c){
          float f = mp[c];
          unsigned bi = __float_as_uint(f);
          bh[c] = (short)(bi >> 16);
          float hif = __uint_as_float(bi & 0xFFFF0000u);
          bl[c] = (short)f2b(f - hif);
        }
        acc = __builtin_amdgcn_mfma_f32_32x32x16_bf16(a, bh, acc, 0, 0, 0);
        acc = __builtin_amdgcn_mfma_f32_32x32x16_bf16(a, bl, acc, 0, 0, 0);
      }
      #pragma unroll
      for (int r = 0; r < 16; ++r){
        int row = (r&3) + 8*(r>>2) + 4*hw;     // t
        d_l[row*33 + col] = acc[r];            // col = i
      }
    }
    __syncthreads();

    // RHS[t][i] = k_t[i_glob] - beta^t * U[t][i] / nk_t   (in place over d_l)
    #pragma unroll
    for (int p = 0; p < 8; ++p){
      int idx = p*128 + tid;
      int t = idx >> 5, i = idx & 31;
      float u = d_l[t*33 + i];
      int jg = ib*32 + i;
      float kti = b2f(k_l[t*256 + (((jg>>3) ^ (t&7))<<3) + (i&7)]);
      float inv = 1.f / (g_l[t*33 + t] + 1e-6f);
      d_l[t*33 + i] = kti - bp[t] * u * inv;
    }
    __syncthreads();

    // forward substitution (I+B) D = RHS; 32 lanes (one column each)
    if (tid < 32){
      const int c = tid;
      for (int t = 1; t < C; ++t){
        float f = 0.1f / (g_l[t*33 + t] + 1e-6f);
        float acc = d_l[t*33 + c];
        for (int s = 0; s < t; ++s)
          acc -= f * bp[t-1-s] * g_l[t*33 + s] * d_l[s*33 + c];
        d_l[t*33 + c] = acc;
      }
    }
    __syncthreads();

    // update: M = bC*M + dM,  dM^T[j][i] = sum_t K[t][j] * (0.1 b^{C-1-t} d[t][i])
    const float bC = bp[C];
    bf16x8 bfr[2];
    #pragma unroll
    for (int h2 = 0; h2 < 2; ++h2){
      #pragma unroll
      for (int c = 0; c < 8; ++c){
        int t = h2*16 + hw*8 + c;
        int ci = C-1-t;
        float w = (ci >= 0) ? 0.1f * bp[ci] : 0.f;
        bfr[h2][c] = (short)f2b(d_l[t*33 + col] * w);   // col = i
      }
    }
    for (int jt = wv*4; jt < wv*4 + 4; ++jt){
      f32x16 acc; for (int r=0;r<16;++r) acc[r]=0.f;
      #pragma unroll
      for (int h2 = 0; h2 < 2; ++h2){
        bf16x8 a;
        int j = jt*32 + col;
        #pragma unroll
        for (int c = 0; c < 8; ++c){
          int t = h2*16 + hw*8 + c;
          a[c] = (short)k_l[t*256 + (((j>>3) ^ (t&7))<<3) + (j&7)];
        }
        acc = __builtin_amdgcn_mfma_f32_32x32x16_bf16(a, bfr[h2], acc, 0, 0, 0);
      }
      #pragma unroll
      for (int r = 0; r < 16; ++r){
        int jrow = jt*32 + (r&3) + 8*(r>>2) + 4*hw;
        int addr = col*257 + jrow;                     // col = i
        M_l[addr] = bC * M_l[addr] + acc[r];
      }
    }
    __syncthreads();
  }

  // y[b][ib*32 + i] = sum_j M[i][j] q[j]
  float* q_l = g_l;
  for (int p = tid; p < 256; p += 128) q_l[p] = b2f(hb[(long)(L_-1)*H_ + p]);
  __syncthreads();
  {
    int i = tid & 31, pt = tid >> 5;
    float s = 0.f;
    const float* mp = &M_l[i*257 + pt*64];
    const float* qp = &q_l[pt*64];
    for (int jj = 0; jj < 64; ++jj) s += mp[jj] * qp[jj];
    d_l[pt*33 + i] = s;
  }
  __syncthreads();
  if (tid < 32){
    float s = d_l[tid] + d_l[33 + tid] + d_l[66 + tid] + d_l[99 + tid];
    y[b*H_ + ib*32 + tid] = san(s);
  }
}

// -------------------------------------------------- z = y @ rp_W + rp_b ------
template<bool F32>
__device__ __forceinline__ void r1_body(
    float* yl, const float* __restrict__ y, const void* __restrict__ rpW,
    const void* __restrict__ rpb, float* __restrict__ zT)
{
  const int b = blockIdx.x, tid = threadIdx.x;
  yl[tid] = san(y[b*H_ + tid]);
  __syncthreads();
  float acc = ldw<F32>(rpb, tid);
  for (int j = 0; j < 256; ++j) acc += yl[j] * ldw<F32>(rpW, (long)j*H_ + tid);
  zT[tid*B_ + b] = san(acc);
}

__global__ __launch_bounds__(256) void r1_kernel(
    const void* __restrict__ embed, const float* __restrict__ y,
    const void* __restrict__ rpW, const void* __restrict__ rpb,
    float* __restrict__ zT)
{
  __shared__ float yl[256];
  if (detect_f32(embed)) r1_body<true >(yl, y, rpW, rpb, zT);
  else                   r1_body<false>(yl, y, rpW, rpb, zT);
}

// ------------------------------------------------ out = z @ out_W + out_b ----
template<bool F32>
__device__ __forceinline__ void r2_body(
    float* zl, const float* __restrict__ zT, const void* __restrict__ outW,
    const void* __restrict__ outb, void* __restrict__ out)
{
  const int tid = threadIdx.x;
  const int v = blockIdx.x*256 + tid;
  for (int idx = tid; idx < 16384; idx += 256) zl[idx] = zT[idx];
  __syncthreads();

  float ob = ldw<F32>(outb, v);
  float acc[64];
  #pragma unroll
  for (int bb = 0; bb < 64; ++bb) acc[bb] = ob;

  for (int i = 0; i < 256; ++i){
    float w = ldw<F32>(outW, (long)i*V_ + v);
    const float4* zp = (const float4*)&zl[i*64];
    #pragma unroll
    for (int q = 0; q < 16; ++q){
      float4 z4 = zp[q];
      acc[q*4+0] += w*z4.x; acc[q*4+1] += w*z4.y;
      acc[q*4+2] += w*z4.z; acc[q*4+3] += w*z4.w;
    }
  }
  if (F32){
    for (int bb = 0; bb < 64; ++bb) ((float*)out)[(long)bb*V_ + v] = san(acc[bb]);
  } else {
    for (int bb = 0; bb < 64; ++bb) ((u16*)out)[(long)bb*V_ + v] = f2b(san(acc[bb]));
  }
}

__global__ __launch_bounds__(256) void r2_kernel(
    const void* __restrict__ embed, const float* __restrict__ zT,
    const void* __restrict__ outW, const void* __restrict__ outb,
    void* __restrict__ out)
{
  __shared__ float zl[16384];
  if (detect_f32(embed)) r2_body<true >(zl, zT, outW, outb, out);
  else                   r2_body<false>(zl, zT, outW, outb, out);
}

// ---------------------------------------------------------------- launch -----
extern "C" void kernel_launch(void* const* d_in, const int* in_sizes, int n_in,
                              void* d_out, int out_size, void* d_ws, size_t ws_size,
                              hipStream_t stream) {
  bool sizes_ok = (n_in == 12) && in_sizes
      && in_sizes[0] == B_*L_ && in_sizes[1] == V_*H_ && in_sizes[2] == H_*2*H_
      && in_sizes[3] == 2*H_  && in_sizes[4] == 2*H_*H_ && in_sizes[5] == H_
      && in_sizes[6] == H_    && in_sizes[7] == H_    && in_sizes[8] == H_*H_
      && in_sizes[9] == H_    && in_sizes[10] == H_*V_ && in_sizes[11] == V_;
  if (!sizes_ok){
    sentinel_kernel<<<(B_*V_ + 255)/256, 256, 0, stream>>>(d_in ? d_in[1] : d_out, d_out, 2000.0f);
    return;
  }
  if (ws_size < 67108864ull){
    sentinel_kernel<<<(B_*V_ + 255)/256, 256, 0, stream>>>(d_in[1], d_out, 1000.0f);
    return;
  }

  const int* seq   = (const int*)d_in[0];
  const void* embed= d_in[1];
  const void* W1   = d_in[2];
  const void* b1   = d_in[3];
  const void* W2   = d_in[4];
  const void* b2   = d_in[5];
  const void* gamma= d_in[6];
  const void* beta = d_in[7];
  const void* rpW  = d_in[8];
  const void* rpb  = d_in[9];
  const void* outW = d_in[10];
  const void* outb = d_in[11];

  u16*   h  = (u16*)d_ws;      // 64 MiB bf16 h; zT reuses ws start after scan
  float* zT = (float*)d_ws;
  float* y  = (float*)d_out;   // 64KB fp32 scratch in d_out, consumed by r1

  enc_kernel <<<4096, 256, 0, stream>>>(seq, embed, W1, b1, W2, b2, gamma, beta, h);
  scan_kernel<<< 512, 128, 0, stream>>>(h, y);
  r1_kernel  <<<  64, 256, 0, stream>>>(embed, y, rpW, rpb, zT);
  r2_kernel  <<< 125, 256, 0, stream>>>(embed, zT, outW, outb, d_out);
}

// Round 6
// 2498.896 us; speedup vs baseline: 2.2804x; 1.4909x over previous
//
#include <hip/hip_runtime.h>

// MomentumDelta: B=64, L=2048, H=256, V=32000, beta=0.9  (fp32 inputs confirmed)
// R6: scan restructured — the chunk-local triangular solve is M-independent,
// so it moves to a parallel pre-kernel (winv) producing W''/sc per chunk.
// scan_big then runs only 3 MFMA phases per chunk with register prefetch.
// Host guard: if ws < 76,021,760 B, fall back to the R5 scan (compiled too).

#define B_ 64
#define L_ 2048
#define H_ 256
#define V_ 32000

typedef unsigned short u16;
typedef __attribute__((ext_vector_type(8))) short bf16x8;
typedef __attribute__((ext_vector_type(16))) float f32x16;

__device__ __forceinline__ float b2f(u16 u){ union{unsigned x; float f;} z; z.x = ((unsigned)u)<<16; return z.f; }
__device__ __forceinline__ u16 f2b(float f){ union{float f; unsigned x;} z; z.f = f; unsigned r = z.x + 0x7FFFu + ((z.x>>16)&1u); return (u16)(r>>16); }
__device__ __forceinline__ float san(float v){ return (v == v && v > -1e30f && v < 1e30f) ? v : 0.f; }

template<bool F32> __device__ __forceinline__ float ldw(const void* p, long i){
  if (F32) return ((const float*)p)[i];
  return b2f(((const u16*)p)[i]);
}
template<bool F32> __device__ __forceinline__ float4 ld4(const void* p, long i){
  if (F32) return *(const float4*)((const float*)p + i);
  ushort4 u = *(const ushort4*)((const u16*)p + i);
  return make_float4(b2f(u.x), b2f(u.y), b2f(u.z), b2f(u.w));
}

__device__ __forceinline__ int detect_f32(const void* embed){
  const u16* e = (const u16*)embed;
  unsigned v = e[2 * (threadIdx.x & 255)];
  int ex = (v >> 7) & 0xFF;
  int pl = (ex >= 0x66 && ex <= 0x7D) || ((v & 0x7FFFu) == 0u);
  int cnt = __syncthreads_count(pl);
  return cnt < 128;
}

// ---------------------------------------------------------------- sentinel --
__global__ __launch_bounds__(256) void sentinel_kernel(const void* embed, void* out, float val)
{
  int f32 = detect_f32(embed);
  long idx = (long)blockIdx.x * 256 + threadIdx.x;
  if (idx < (long)B_ * V_){
    if (f32) ((float*)out)[idx] = val;
    else     ((u16*)out)[idx]   = f2b(val);
  }
}

// ---------------------------------------------------------------- encoder ---
template<bool F32>
__device__ __forceinline__ void enc_body(
    u16* sm,
    const int* __restrict__ seq, const void* __restrict__ embed,
    const void* __restrict__ W1, const void* __restrict__ b1,
    const void* __restrict__ W2, const void* __restrict__ b2,
    const void* __restrict__ gamma, const void* __restrict__ beta,
    u16* __restrict__ h)
{
  u16* eT  = sm;           // [256][32]
  u16* t1T = sm + 8192;    // [512][32]
  u16* xb  = sm + 24576;   // [32][256]
  float* stats = (float*)sm;

  const int tid = threadIdx.x;
  const long tok0 = (long)blockIdx.x * 32;

  for (int idx = tid; idx < 8192; idx += 256){
    int r = idx >> 8, c = idx & 255;
    int tk = seq[tok0 + r];
    tk = (tk >= 0 && tk < V_) ? tk : 0;
    eT[c*32 + r] = f2b(ldw<F32>(embed, (long)tk*H_ + c));
  }
  __syncthreads();

  const int jg = tid & 31, rg = tid >> 5;
  const int r0 = rg * 4;

  for (int sl = 0; sl < 4; ++sl){
    const int j0 = sl*128 + jg*4;
    float acc[4][4] = {{0.f}};
    for (int c = 0; c < 256; ++c){
      ushort4 a4 = *(const ushort4*)&eT[c*32 + r0];
      float4 w = ld4<F32>(W1, (long)c*512 + j0);
      float a0=b2f(a4.x), a1=b2f(a4.y), a2=b2f(a4.z), a3=b2f(a4.w);
      acc[0][0]+=a0*w.x; acc[0][1]+=a0*w.y; acc[0][2]+=a0*w.z; acc[0][3]+=a0*w.w;
      acc[1][0]+=a1*w.x; acc[1][1]+=a1*w.y; acc[1][2]+=a1*w.z; acc[1][3]+=a1*w.w;
      acc[2][0]+=a2*w.x; acc[2][1]+=a2*w.y; acc[2][2]+=a2*w.z; acc[2][3]+=a2*w.w;
      acc[3][0]+=a3*w.x; acc[3][1]+=a3*w.y; acc[3][2]+=a3*w.z; acc[3][3]+=a3*w.w;
    }
    for (int jj = 0; jj < 4; ++jj){
      float bb = ldw<F32>(b1, j0+jj);
      ushort4 o;
      o.x = f2b(fmaxf(acc[0][jj]+bb, 0.f));
      o.y = f2b(fmaxf(acc[1][jj]+bb, 0.f));
      o.z = f2b(fmaxf(acc[2][jj]+bb, 0.f));
      o.w = f2b(fmaxf(acc[3][jj]+bb, 0.f));
      *(ushort4*)&t1T[(j0+jj)*32 + r0] = o;
    }
  }
  __syncthreads();

  for (int sl = 0; sl < 2; ++sl){
    const int co0 = sl*128 + jg*4;
    float acc[4][4] = {{0.f}};
    for (int c = 0; c < 512; ++c){
      ushort4 a4 = *(const ushort4*)&t1T[c*32 + r0];
      float4 w = ld4<F32>(W2, (long)c*256 + co0);
      float a0=b2f(a4.x), a1=b2f(a4.y), a2=b2f(a4.z), a3=b2f(a4.w);
      acc[0][0]+=a0*w.x; acc[0][1]+=a0*w.y; acc[0][2]+=a0*w.z; acc[0][3]+=a0*w.w;
      acc[1][0]+=a1*w.x; acc[1][1]+=a1*w.y; acc[1][2]+=a1*w.z; acc[1][3]+=a1*w.w;
      acc[2][0]+=a2*w.x; acc[2][1]+=a2*w.y; acc[2][2]+=a2*w.z; acc[2][3]+=a2*w.w;
      acc[3][0]+=a3*w.x; acc[3][1]+=a3*w.y; acc[3][2]+=a3*w.z; acc[3][3]+=a3*w.w;
    }
    float bb0 = ldw<F32>(b2, co0+0), bb1 = ldw<F32>(b2, co0+1);
    float bb2 = ldw<F32>(b2, co0+2), bb3 = ldw<F32>(b2, co0+3);
    for (int rr = 0; rr < 4; ++rr){
      float x0 = acc[rr][0] + bb0 + b2f(eT[(co0+0)*32 + r0+rr]);
      float x1 = acc[rr][1] + bb1 + b2f(eT[(co0+1)*32 + r0+rr]);
      float x2 = acc[rr][2] + bb2 + b2f(eT[(co0+2)*32 + r0+rr]);
      float x3 = acc[rr][3] + bb3 + b2f(eT[(co0+3)*32 + r0+rr]);
      ushort4 o; o.x=f2b(x0); o.y=f2b(x1); o.z=f2b(x2); o.w=f2b(x3);
      *(ushort4*)&xb[(r0+rr)*256 + co0] = o;
    }
  }
  __syncthreads();

  if (tid < 32){
    float s = 0.f, q = 0.f;
    for (int c = 0; c < 256; ++c){ float v = b2f(xb[tid*256 + c]); s += v; q += v*v; }
    float mu = s * (1.f/256.f);
    float var = q * (1.f/256.f) - mu*mu;
    stats[tid] = mu;
    stats[32 + tid] = 1.f / sqrtf(fmaxf(var, 0.f) + 1e-5f);
  }
  __syncthreads();
  for (int idx = tid; idx < 8192; idx += 256){
    int r = idx >> 8, c = idx & 255;
    float hv = (b2f(xb[idx]) - stats[r]) * stats[32+r] * ldw<F32>(gamma, c) + ldw<F32>(beta, c);
    h[(tok0 + r)*H_ + c] = f2b(san(hv));
  }
}

__global__ __launch_bounds__(256) void enc_kernel(
    const int* __restrict__ seq, const void* __restrict__ embed,
    const void* __restrict__ W1, const void* __restrict__ b1,
    const void* __restrict__ W2, const void* __restrict__ b2,
    const void* __restrict__ gamma, const void* __restrict__ beta,
    u16* __restrict__ h)
{
  __shared__ __align__(16) u16 sm[32768];
  if (detect_f32(embed)) enc_body<true >(sm, seq, embed, W1, b1, W2, b2, gamma, beta, h);
  else                   enc_body<false>(sm, seq, embed, W1, b1, W2, b2, gamma, beta, h);
}

// ------------------------------------------------- winv pre-kernel ----------
// grid 4096 = b*64 + ch, 64 threads.  Computes per chunk:
//   W''[t][s] = 0.1*beta^{C-1-t} * ((I+B)^-1)[t][s]  (bf16, lower-tri, rows<C)
//   sc[t]     = beta^t / (|k_t|^2 + 1e-6)
__global__ __launch_bounds__(64) void winv_kernel(
    const u16* __restrict__ h, u16* __restrict__ w2g, float* __restrict__ scg)
{
  __shared__ __align__(16) u16 k_l[32*256];
  __shared__ float g_l[32*33];
  __shared__ float w_l[32*33];
  __shared__ float bp[33];

  const int tid = threadIdx.x;
  const int cb = blockIdx.x;
  const int b = cb >> 6, ch = cb & 63;
  const int col = tid & 31, hw = tid >> 5;
  const int C = (ch == 63) ? 31 : 32;

  if (tid < 33) bp[tid] = powf(0.9f, (float)tid);

  { // stage K (XOR-swizzled 16B units), rows >= C zeroed
    const int t = tid >> 1, u0 = (tid & 1) * 16;
    const u16* src = h + ((long)b*L_ + ch*32 + t)*H_ + u0*8;
    #pragma unroll
    for (int c = 0; c < 16; ++c){
      uint4 v = make_uint4(0u,0u,0u,0u);
      if (t < C) v = *(const uint4*)(src + c*8);
      int phys = (u0 + c) ^ (t & 7);
      *(uint4*)&k_l[t*256 + phys*8] = v;
    }
  }
  __syncthreads();

  { // G = K K^T via MFMA (single wave)
    f32x16 acc; for (int r = 0; r < 16; ++r) acc[r] = 0.f;
    #pragma unroll
    for (int s = 0; s < 16; ++s){
      int phys = (s*2 + hw) ^ (col & 7);
      bf16x8 a = *(const bf16x8*)&k_l[col*256 + phys*8];
      acc = __builtin_amdgcn_mfma_f32_32x32x16_bf16(a, a, acc, 0, 0, 0);
    }
    #pragma unroll
    for (int r = 0; r < 16; ++r){
      int row = (r&3) + 8*(r>>2) + 4*hw;
      g_l[row*33 + col] = acc[r];
    }
  }
  __syncthreads();

  // forward substitution: column c of W = (I+B)^-1
  if (tid < 32){
    const int c = tid;
    for (int t = 0; t < 32; ++t){
      float acc = (t == c) ? 1.f : 0.f;
      if (t > c){
        float f = 0.1f / (g_l[t*33 + t] + 1e-6f);
        for (int s = c; s < t; ++s)
          acc -= f * bp[t-1-s] * g_l[t*33 + s] * w_l[s*33 + c];
      }
      w_l[t*33 + c] = acc;
    }
    scg[(long)cb*32 + c] = bp[c] / (g_l[c*33 + c] + 1e-6f);
  }
  __syncthreads();

  for (int idx = tid; idx < 1024; idx += 64){
    int t = idx >> 5, s = idx & 31;
    float v = 0.f;
    if (t < C && s <= t) v = 0.1f * bp[C-1-t] * w_l[t*33 + s];
    w2g[(long)cb*1024 + idx] = f2b(v);
  }
}

// ------------------------------------------------------- scan (big path) ----
// grid 512: b = idx&63 (XCD-local siblings), ib = idx>>6.  256 thr / 4 waves.
// Per chunk: U = K M^T (hi/lo split over 4 waves, LDS-atomic reduce) ->
// RHS hi/lo -> Dw = W'' RHS (wave0) -> M RMW update.  K/W''/sc reg-prefetch.
__global__ __launch_bounds__(256) void scan_big(
    const u16* __restrict__ h, const u16* __restrict__ w2g,
    const float* __restrict__ scg, float* __restrict__ y)
{
  __shared__ __align__(16) float M_l[32*260];      // [i][j] fp32, stride 260
  __shared__ __align__(16) u16   k_l[32*256];      // [t][j] bf16, XOR-swizzled
  __shared__ float u_p[32*33];                     // U partials [t][i]
  __shared__ __align__(16) u16   rhsT_hi[32*32];   // [i][s]
  __shared__ __align__(16) u16   rhsT_lo[32*32];
  __shared__ __align__(16) u16   w2_l[32*32];      // [t][s]
  __shared__ __align__(16) u16   dwT[32*32];       // [i][t]
  __shared__ float sc_l[32];
  __shared__ float bp[33];

  const int tid = threadIdx.x;
  const int b = blockIdx.x & 63, ib = blockIdx.x >> 6;
  const int lane = tid & 63, wv = tid >> 6;
  const int col = lane & 31, hw = lane >> 5;

  if (tid < 33) bp[tid] = powf(0.9f, (float)tid);
  const u16*  hb  = h   + (long)b * L_ * H_;
  const u16*  w2b = w2g + (long)b * 64 * 1024;
  const float* scb = scg + (long)b * 64 * 32;

  for (int idx = tid; idx < 32*260; idx += 256) M_l[idx] = 0.f;

  const int st  = tid >> 3;          // staged t-row
  const int su0 = (tid & 7) * 4;     // first 16B unit

  { // stage chunk 0 (all rows < 2047)
    const u16* src = hb + (long)st * H_ + su0 * 8;
    #pragma unroll
    for (int c = 0; c < 4; ++c){
      uint4 v = *(const uint4*)(src + c*8);
      int phys = (su0 + c) ^ (st & 7);
      *(uint4*)&k_l[st*256 + phys*8] = v;
    }
    *(uint2*)&w2_l[tid*4] = *(const uint2*)(w2b + tid*4);
    if (tid < 32) sc_l[tid] = scb[tid];
    for (int idx = tid; idx < 32*33; idx += 256) u_p[idx] = 0.f;
  }
  __syncthreads();

  for (int ch = 0; ch < 64; ++ch){
    const float bC = (ch == 63) ? bp[31] : bp[32];

    // prefetch next chunk into registers (latency overlapped with phases A-D)
    uint4 pf[4]; uint2 pw; float psc = 0.f;
    {
      const int chn = (ch < 63) ? ch + 1 : 63;
      const long tg = (long)chn*32 + st;
      const u16* src = hb + tg * H_ + su0 * 8;
      #pragma unroll
      for (int c = 0; c < 4; ++c) pf[c] = *(const uint4*)(src + c*8);
      if (tg >= 2047){
        #pragma unroll
        for (int c = 0; c < 4; ++c) pf[c] = make_uint4(0u,0u,0u,0u);
      }
      pw = *(const uint2*)(w2b + chn*1024 + tid*4);
      if (tid < 32) psc = scb[chn*32 + tid];
    }

    // ---- phase A: U partials (wave: jblk = wv&1, part(hi/lo) = wv>>1)
    {
      const int jblk = wv & 1, part = wv >> 1;
      f32x16 acc; for (int r = 0; r < 16; ++r) acc[r] = 0.f;
      #pragma unroll
      for (int s8 = 0; s8 < 8; ++s8){
        int j16 = jblk*8 + s8;
        int phys = (j16*2 + hw) ^ (col & 7);
        bf16x8 a = *(const bf16x8*)&k_l[col*256 + phys*8];    // col = t
        int j0 = j16*16 + hw*8;
        float4 m0 = *(const float4*)&M_l[col*260 + j0];       // col = i
        float4 m1 = *(const float4*)&M_l[col*260 + j0 + 4];
        float mv[8] = {m0.x,m0.y,m0.z,m0.w,m1.x,m1.y,m1.z,m1.w};
        bf16x8 bf;
        #pragma unroll
        for (int c = 0; c < 8; ++c){
          unsigned bi = __float_as_uint(mv[c]);
          if (part == 0) bf[c] = (short)(bi >> 16);
          else {
            float hif = __uint_as_float(bi & 0xFFFF0000u);
            bf[c] = (short)f2b(mv[c] - hif);
          }
        }
        acc = __builtin_amdgcn_mfma_f32_32x32x16_bf16(a, bf, acc, 0, 0, 0);
      }
      #pragma unroll
      for (int r = 0; r < 16; ++r){
        int trow = (r&3) + 8*(r>>2) + 4*hw;
        atomicAdd(&u_p[trow*33 + col], acc[r]);
      }
    }
    __syncthreads();

    // ---- phase B: RHS[t][i] = k_t[i_glob] - sc_t*U[t][i], hi/lo -> rhsT
    {
      const int i = tid >> 3, t0 = (tid & 7) * 4;
      const int jg = ib*32 + i;
      ushort4 hh, ll;
      #pragma unroll
      for (int c = 0; c < 4; ++c){
        int t = t0 + c;
        float u = u_p[t*33 + i];
        float kti = b2f(k_l[t*256 + (((jg>>3) ^ (t&7))<<3) + (jg&7)]);
        float r = kti - sc_l[t]*u;
        unsigned bi = __float_as_uint(r);
        u16 hi = (u16)(bi >> 16);
        float hif = __uint_as_float((unsigned)hi << 16);
        u16 lo = f2b(r - hif);
        (&hh.x)[c] = hi; (&ll.x)[c] = lo;
      }
      *(ushort4*)&rhsT_hi[i*32 + t0] = hh;
      *(ushort4*)&rhsT_lo[i*32 + t0] = ll;
    }
    __syncthreads();

    // ---- phase C: Dw = W'' x RHS (wave0 only; 4 MFMAs)
    if (wv == 0){
      f32x16 dacc; for (int r = 0; r < 16; ++r) dacc[r] = 0.f;
      #pragma unroll
      for (int ks = 0; ks < 2; ++ks){
        int s0 = ks*16 + hw*8;
        bf16x8 aw = *(const bf16x8*)&w2_l[col*32 + s0];       // col = t
        bf16x8 bh = *(const bf16x8*)&rhsT_hi[col*32 + s0];    // col = i
        bf16x8 bl = *(const bf16x8*)&rhsT_lo[col*32 + s0];
        dacc = __builtin_amdgcn_mfma_f32_32x32x16_bf16(aw, bh, dacc, 0, 0, 0);
        dacc = __builtin_amdgcn_mfma_f32_32x32x16_bf16(aw, bl, dacc, 0, 0, 0);
      }
      #pragma unroll
      for (int g = 0; g < 4; ++g){
        ushort4 o;
        o.x = f2b(dacc[4*g+0]); o.y = f2b(dacc[4*g+1]);
        o.z = f2b(dacc[4*g+2]); o.w = f2b(dacc[4*g+3]);
        *(ushort4*)&dwT[col*32 + 8*g + 4*hw] = o;             // [i][t]
      }
    }
    __syncthreads();

    // ---- phase D: M = bC*M + K^T Dw  (2 j-tiles per wave)
    {
      bf16x8 bD[2];
      #pragma unroll
      for (int ks = 0; ks < 2; ++ks)
        bD[ks] = *(const bf16x8*)&dwT[col*32 + ks*16 + hw*8]; // col = i
      #pragma unroll
      for (int tile = 0; tile < 2; ++tile){
        const int jt = wv*2 + tile;
        const int j = jt*32 + col;                            // col = j-local
        f32x16 macc; for (int r = 0; r < 16; ++r) macc[r] = 0.f;
        #pragma unroll
        for (int ks = 0; ks < 2; ++ks){
          bf16x8 aK;
          #pragma unroll
          for (int c = 0; c < 8; ++c){
            int t = ks*16 + hw*8 + c;
            aK[c] = (short)k_l[t*256 + (((j>>3) ^ (t&7))<<3) + (j&7)];
          }
          macc = __builtin_amdgcn_mfma_f32_32x32x16_bf16(aK, bD[ks], macc, 0, 0, 0);
        }
        #pragma unroll
        for (int g = 0; g < 4; ++g){
          int addr = col*260 + jt*32 + 8*g + 4*hw;            // col = i
          float4 mv = *(float4*)&M_l[addr];
          mv.x = bC*mv.x + macc[4*g+0];
          mv.y = bC*mv.y + macc[4*g+1];
          mv.z = bC*mv.z + macc[4*g+2];
          mv.w = bC*mv.w + macc[4*g+3];
          *(float4*)&M_l[addr] = mv;
        }
      }
    }
    __syncthreads();

    // ---- commit prefetched chunk to LDS, re-zero u_p
    {
      #pragma unroll
      for (int c = 0; c < 4; ++c){
        int phys = (su0 + c) ^ (st & 7);
        *(uint4*)&k_l[st*256 + phys*8] = pf[c];
      }
      *(uint2*)&w2_l[tid*4] = pw;
      if (tid < 32) sc_l[tid] = psc;
      for (int idx = tid; idx < 32*33; idx += 256) u_p[idx] = 0.f;
    }
    __syncthreads();
  }

  // ---- epilogue: y[b][ib*32+i] = sum_j M[i][j] q[j]
  float* q_l = u_p;          // reuse (u_p[0..255])
  float* par = u_p + 512;    // u_p[512..767]
  q_l[tid] = b2f(hb[(long)(L_-1)*H_ + tid]);
  __syncthreads();
  {
    int i = tid & 31, pt = tid >> 5;
    float s = 0.f;
    const float* mp = &M_l[i*260 + pt*32];
    const float* qp = &q_l[pt*32];
    #pragma unroll
    for (int jj = 0; jj < 32; ++jj) s += mp[jj] * qp[jj];
    par[pt*32 + i] = s;
  }
  __syncthreads();
  if (tid < 32){
    float s = 0.f;
    #pragma unroll
    for (int pt = 0; pt < 8; ++pt) s += par[pt*32 + tid];
    y[b*H_ + ib*32 + tid] = san(s);
  }
}

// ------------------------------------------------ scan fallback (R5 path) ---
__global__ __launch_bounds__(128) void scan_fallback(
    const u16* __restrict__ h, float* __restrict__ y)
{
  __shared__ __align__(16) float M_l[32*257];
  __shared__ __align__(16) u16  k_l[32*256];
  __shared__ float d_l[32*33];
  __shared__ float g_l[32*33];
  __shared__ float bp[33];

  const int tid = threadIdx.x;
  const int b = blockIdx.x & 63, ib = blockIdx.x >> 6;
  const int lane = tid & 63, wv = tid >> 6;
  const int col = lane & 31, hw = lane >> 5;

  for (int idx = tid; idx < 32*257; idx += 128) M_l[idx] = 0.f;
  if (tid < 33) bp[tid] = powf(0.9f, (float)tid);
  const u16* hb = h + (long)b * L_ * H_;
  __syncthreads();

  for (int ch = 0; ch < 64; ++ch){
    const int t0 = ch*32;
    const int C = (2047 - t0 < 32) ? (2047 - t0) : 32;

    {
      const int t = tid >> 2, j0 = (tid & 3) * 64;
      const uint4* gp = (const uint4*)(hb + (long)(t0 + t)*H_ + j0);
      #pragma unroll
      for (int c = 0; c < 8; ++c){
        uint4 v = (t < C) ? gp[c] : make_uint4(0u,0u,0u,0u);
        int phys = ((j0 >> 3) + c) ^ (t & 7);
        *(uint4*)&k_l[t*256 + phys*8] = v;
      }
    }
    __syncthreads();

    if (wv == 1){
      f32x16 acc; for (int r=0;r<16;++r) acc[r]=0.f;
      #pragma unroll
      for (int s = 0; s < 16; ++s){
        int phys = (s*2 + hw) ^ (col & 7);
        bf16x8 a = *(const bf16x8*)&k_l[col*256 + phys*8];
        acc = __builtin_amdgcn_mfma_f32_32x32x16_bf16(a, a, acc, 0, 0, 0);
      }
      #pragma unroll
      for (int r = 0; r < 16; ++r){
        int row = (r&3) + 8*(r>>2) + 4*hw;
        g_l[row*33 + col] = acc[r];
      }
    } else {
      f32x16 acc; for (int r=0;r<16;++r) acc[r]=0.f;
      for (int s = 0; s < 16; ++s){
        int phys = (s*2 + hw) ^ (col & 7);
        bf16x8 a = *(const bf16x8*)&k_l[col*256 + phys*8];
        bf16x8 bh, bl;
        const float* mp = &M_l[col*257 + s*16 + hw*8];
        #pragma unroll
        for (int c = 0; c < 8; ++c){
          float f = mp[c];
          unsigned bi = __float_as_uint(f);
          bh[c] = (short)(bi >> 16);
          float hif = __uint_as_float(bi & 0xFFFF0000u);
          bl[c] = (short)f2b(f - hif);
        }
        acc = __builtin_amdgcn_mfma_f32_32x32x16_bf16(a, bh, acc, 0, 0, 0);
        acc = __builtin_amdgcn_mfma_f32_32x32x16_bf16(a, bl, acc, 0, 0, 0);
      }
      #pragma unroll
      for (int r = 0; r < 16; ++r){
        int row = (r&3) + 8*(r>>2) + 4*hw;
        d_l[row*33 + col] = acc[r];
      }
    }
    __syncthreads();

    #pragma unroll
    for (int p = 0; p < 8; ++p){
      int idx = p*128 + tid;
      int t = idx >> 5, i = idx & 31;
      float u = d_l[t*33 + i];
      int jg = ib*32 + i;
      float kti = b2f(k_l[t*256 + (((jg>>3) ^ (t&7))<<3) + (jg&7)]);
      float inv = 1.f / (g_l[t*33 + t] + 1e-6f);
      d_l[t*33 + i] = kti - bp[t] * u * inv;
    }
    __syncthreads();

    if (tid < 32){
      const int c = tid;
      for (int t = 1; t < C; ++t){
        float f = 0.1f / (g_l[t*33 + t] + 1e-6f);
        float acc = d_l[t*33 + c];
        for (int s = 0; s < t; ++s)
          acc -= f * bp[t-1-s] * g_l[t*33 + s] * d_l[s*33 + c];
        d_l[t*33 + c] = acc;
      }
    }
    __syncthreads();

    {
      const float bC = bp[C];
      bf16x8 bfr[2];
      #pragma unroll
      for (int h2 = 0; h2 < 2; ++h2){
        #pragma unroll
        for (int c = 0; c < 8; ++c){
          int t = h2*16 + hw*8 + c;
          int ci = C-1-t;
          float w = (ci >= 0) ? 0.1f * bp[ci] : 0.f;
          bfr[h2][c] = (short)f2b(d_l[t*33 + col] * w);
        }
      }
      for (int jt = wv*4; jt < wv*4 + 4; ++jt){
        f32x16 acc; for (int r=0;r<16;++r) acc[r]=0.f;
        #pragma unroll
        for (int h2 = 0; h2 < 2; ++h2){
          bf16x8 a;
          int j = jt*32 + col;
          #pragma unroll
          for (int c = 0; c < 8; ++c){
            int t = h2*16 + hw*8 + c;
            a[c] = (short)k_l[t*256 + (((j>>3) ^ (t&7))<<3) + (j&7)];
          }
          acc = __builtin_amdgcn_mfma_f32_32x32x16_bf16(a, bfr[h2], acc, 0, 0, 0);
        }
        #pragma unroll
        for (int r = 0; r < 16; ++r){
          int jrow = jt*32 + (r&3) + 8*(r>>2) + 4*hw;
          int addr = col*257 + jrow;
          M_l[addr] = bC * M_l[addr] + acc[r];
        }
      }
    }
    __syncthreads();
  }

  float* q_l = g_l;
  for (int p = tid; p < 256; p += 128) q_l[p] = b2f(hb[(long)(L_-1)*H_ + p]);
  __syncthreads();
  {
    int i = tid & 31, pt = tid >> 5;
    float s = 0.f;
    const float* mp = &M_l[i*257 + pt*64];
    const float* qp = &q_l[pt*64];
    for (int jj = 0; jj < 64; ++jj) s += mp[jj] * qp[jj];
    d_l[pt*33 + i] = s;
  }
  __syncthreads();
  if (tid < 32){
    float s = d_l[tid] + d_l[33 + tid] + d_l[66 + tid] + d_l[99 + tid];
    y[b*H_ + ib*32 + tid] = san(s);
  }
}

// -------------------------------------------------- z = y @ rp_W + rp_b ------
template<bool F32>
__device__ __forceinline__ void r1_body(
    float* yl, const float* __restrict__ y, const void* __restrict__ rpW,
    const void* __restrict__ rpb, float* __restrict__ zT)
{
  const int b = blockIdx.x, tid = threadIdx.x;
  yl[tid] = san(y[b*H_ + tid]);
  __syncthreads();
  float acc = ldw<F32>(rpb, tid);
  for (int j = 0; j < 256; ++j) acc += yl[j] * ldw<F32>(rpW, (long)j*H_ + tid);
  zT[tid*B_ + b] = san(acc);
}

__global__ __launch_bounds__(256) void r1_kernel(
    const void* __restrict__ embed, const float* __restrict__ y,
    const void* __restrict__ rpW, const void* __restrict__ rpb,
    float* __restrict__ zT)
{
  __shared__ float yl[256];
  if (detect_f32(embed)) r1_body<true >(yl, y, rpW, rpb, zT);
  else                   r1_body<false>(yl, y, rpW, rpb, zT);
}

// ------------------------------------------------ out = z @ out_W + out_b ----
template<bool F32>
__device__ __forceinline__ void r2_body(
    float* zl, const float* __restrict__ zT, const void* __restrict__ outW,
    const void* __restrict__ outb, void* __restrict__ out)
{
  const int tid = threadIdx.x;
  const int v = blockIdx.x*256 + tid;
  for (int idx = tid; idx < 16384; idx += 256) zl[idx] = zT[idx];
  __syncthreads();

  float ob = ldw<F32>(outb, v);
  float acc[64];
  #pragma unroll
  for (int bb = 0; bb < 64; ++bb) acc[bb] = ob;

  for (int i = 0; i < 256; ++i){
    float w = ldw<F32>(outW, (long)i*V_ + v);
    const float4* zp = (const float4*)&zl[i*64];
    #pragma unroll
    for (int q = 0; q < 16; ++q){
      float4 z4 = zp[q];
      acc[q*4+0] += w*z4.x; acc[q*4+1] += w*z4.y;
      acc[q*4+2] += w*z4.z; acc[q*4+3] += w*z4.w;
    }
  }
  if (F32){
    for (int bb = 0; bb < 64; ++bb) ((float*)out)[(long)bb*V_ + v] = san(acc[bb]);
  } else {
    for (int bb = 0; bb < 64; ++bb) ((u16*)out)[(long)bb*V_ + v] = f2b(san(acc[bb]));
  }
}

__global__ __launch_bounds__(256) void r2_kernel(
    const void* __restrict__ embed, const float* __restrict__ zT,
    const void* __restrict__ outW, const void* __restrict__ outb,
    void* __restrict__ out)
{
  __shared__ float zl[16384];
  if (detect_f32(embed)) r2_body<true >(zl, zT, outW, outb, out);
  else                   r2_body<false>(zl, zT, outW, outb, out);
}

// ---------------------------------------------------------------- launch -----
extern "C" void kernel_launch(void* const* d_in, const int* in_sizes, int n_in,
                              void* d_out, int out_size, void* d_ws, size_t ws_size,
                              hipStream_t stream) {
  bool sizes_ok = (n_in == 12) && in_sizes
      && in_sizes[0] == B_*L_ && in_sizes[1] == V_*H_ && in_sizes[2] == H_*2*H_
      && in_sizes[3] == 2*H_  && in_sizes[4] == 2*H_*H_ && in_sizes[5] == H_
      && in_sizes[6] == H_    && in_sizes[7] == H_    && in_sizes[8] == H_*H_
      && in_sizes[9] == H_    && in_sizes[10] == H_*V_ && in_sizes[11] == V_;
  if (!sizes_ok){
    sentinel_kernel<<<(B_*V_ + 255)/256, 256, 0, stream>>>(d_in ? d_in[1] : d_out, d_out, 2000.0f);
    return;
  }
  if (ws_size < 67108864ull){
    sentinel_kernel<<<(B_*V_ + 255)/256, 256, 0, stream>>>(d_in[1], d_out, 1000.0f);
    return;
  }

  const int* seq   = (const int*)d_in[0];
  const void* embed= d_in[1];
  const void* W1   = d_in[2];
  const void* b1   = d_in[3];
  const void* W2   = d_in[4];
  const void* b2   = d_in[5];
  const void* gamma= d_in[6];
  const void* beta = d_in[7];
  const void* rpW  = d_in[8];
  const void* rpb  = d_in[9];
  const void* outW = d_in[10];
  const void* outb = d_in[11];

  u16*   h  = (u16*)d_ws;      // 64 MiB bf16 h; zT reuses ws start after scan
  float* zT = (float*)d_ws;
  float* y  = (float*)d_out;   // fp32 scratch in d_out, consumed by r1

  enc_kernel<<<4096, 256, 0, stream>>>(seq, embed, W1, b1, W2, b2, gamma, beta, h);

  const size_t need = 67108864ull + 8388608ull + 524288ull;  // h + W'' + sc
  if (ws_size >= need){
    u16*   w2g = (u16*)  ((char*)d_ws + 67108864);
    float* scg = (float*)((char*)d_ws + 67108864 + 8388608);
    winv_kernel<<<4096, 64, 0, stream>>>(h, w2g, scg);
    scan_big  <<< 512, 256, 0, stream>>>(h, w2g, scg, y);
  } else {
    scan_fallback<<<512, 128, 0, stream>>>(h, y);
  }

  r1_kernel<<< 64, 256, 0, stream>>>(embed, y, rpW, rpb, zT);
  r2_kernel<<<125, 256, 0, stream>>>(embed, zT, outW, outb, d_out);
}